// Round 1
// baseline (547.412 us; speedup 1.0000x reference)
//
#include <hip/hip_runtime.h>
#include <math.h>

#define BITS 12
#define NUM_CODES 4096
#define ROWS (4 * 8192)            // b*s positions
#define NATF 0.69314718055994530942f

// One wave (64 threads) per row. Lanes 0..11 compute the sampled bit via
// rand <= sigmoid(logit); __ballot bit k == bit k of the code index, so the
// power-of-two sum is free. All 64 lanes then stream the 4096-float one-hot
// row with float4 stores (64 lanes * 16B = 1 KiB contiguous per instruction,
// full 64B lines -> pure write traffic, no read-allocate).
__global__ __launch_bounds__(64)
void onehot_kernel(const float* __restrict__ logits,
                   const float* __restrict__ rand_unif,
                   float* __restrict__ out)
{
    const int row  = blockIdx.x;
    const int lane = threadIdx.x;

    bool pred = false;
    if (lane < BITS) {
        float x = logits[row * BITS + lane];
        float r = rand_unif[row * BITS + lane];
        // fp64 sigmoid rounded to fp32: best match to the fp32 numpy reference
        // at rand ~ p decision boundaries.
        float p = (float)(1.0 / (1.0 + exp(-(double)x)));
        pred = (r <= p);
    }
    unsigned long long b = __ballot(pred);
    int idx = (int)(b & 0xFFFu) | (int)((b >> 4) & 0xF00u); // lanes 0..11 -> bits 0..11
    // (lanes 0..11 occupy ballot bits 0..11 directly; mask the rest)
    idx = (int)(b & 0xFFFULL);

    float* __restrict__ rowp = out + (size_t)row * NUM_CODES;
    #pragma unroll
    for (int i = 0; i < 16; ++i) {
        int base = i * 256 + lane * 4;
        float4 v = make_float4(0.f, 0.f, 0.f, 0.f);
        int d = idx - base;
        if (d >= 0 && d < 4) ((float*)&v)[d] = 1.0f;
        *(float4*)(rowp + base) = v;
    }
}

// aux_kl_loss = mean over positions of relu(BITS*ln2 - entropy - ln2).
// 32768 positions, one thread each; wave shuffle reduce -> LDS -> one
// atomicAdd per 256-thread block (128 atomics total).
__global__ __launch_bounds__(256)
void loss_kernel(const float* __restrict__ logits, float* __restrict__ loss_out)
{
    int pos = blockIdx.x * blockDim.x + threadIdx.x;
    float contrib = 0.f;
    if (pos < ROWS) {
        const float* lg = logits + pos * BITS;
        float H = 0.f;
        #pragma unroll
        for (int k = 0; k < BITS; ++k) {
            float x  = lg[k];
            float ax = fabsf(x);
            float e  = expf(-ax);
            // binary entropy of sigmoid(x): log1p(e^-|x|) + |x| * sigma(-|x|)
            H += log1pf(e) + ax * (e / (1.f + e));
        }
        float kl     = BITS * NATF - H;
        float hinged = kl - NATF;
        contrib = (hinged > 0.f) ? hinged * (1.f / (float)ROWS) : 0.f;
    }
    #pragma unroll
    for (int off = 32; off > 0; off >>= 1)
        contrib += __shfl_down(contrib, off, 64);

    __shared__ float ws[4];
    int wave = threadIdx.x >> 6;
    if ((threadIdx.x & 63) == 0) ws[wave] = contrib;
    __syncthreads();
    if (threadIdx.x == 0) {
        float s = ws[0] + ws[1] + ws[2] + ws[3];
        atomicAdd(loss_out, s);
    }
}

extern "C" void kernel_launch(void* const* d_in, const int* in_sizes, int n_in,
                              void* d_out, int out_size, void* d_ws, size_t ws_size,
                              hipStream_t stream)
{
    const float* logits    = (const float*)d_in[0];
    const float* rand_unif = (const float*)d_in[1];
    float* out = (float*)d_out;
    float* loss_out = out + (size_t)ROWS * NUM_CODES;  // element 134217728

    // zero the scalar accumulator (d_out is poisoned with 0xAA each call)
    hipMemsetAsync((void*)loss_out, 0, sizeof(float), stream);

    loss_kernel<<<ROWS / 256, 256, 0, stream>>>(logits, loss_out);
    onehot_kernel<<<ROWS, 64, 0, stream>>>(logits, rand_unif, out);
}

// Round 3
// 533.282 us; speedup vs baseline: 1.0265x; 1.0265x over previous
//
#include <hip/hip_runtime.h>
#include <math.h>

#define BITS 12
#define NUM_CODES 4096
#define ROWS (4 * 8192)            // b*s positions
#define NATF 0.69314718055994530942f

typedef float v4f __attribute__((ext_vector_type(4)));   // native vec for nontemporal builtin

// 256-thread blocks, 4 waves; each wave owns one row. Lanes 0..11 compute the
// sampled bit via rand <= sigmoid(logit); __ballot bit k == bit k of the code
// index (power-of-two sum is free). All 64 lanes stream the 4096-float one-hot
// row with nontemporal float4 stores (1 KiB/instr/wave, full 64B lines).
// Per-element STATIC compares — no dynamic register indexing (round-1 suspect:
// dynamic insertelement can lower to scratch traffic).
__global__ __launch_bounds__(256)
void onehot_kernel(const float* __restrict__ logits,
                   const float* __restrict__ rand_unif,
                   float* __restrict__ out)
{
    const int wave = threadIdx.x >> 6;
    const int lane = threadIdx.x & 63;
    const int row  = blockIdx.x * 4 + wave;

    bool pred = false;
    if (lane < BITS) {
        float x = logits[row * BITS + lane];
        float r = rand_unif[row * BITS + lane];
        // fp64 sigmoid rounded to fp32: matches the fp32 numpy reference at
        // rand ~ p decision boundaries (absmax 0.0 in round 1).
        float p = (float)(1.0 / (1.0 + exp(-(double)x)));
        pred = (r <= p);
    }
    unsigned long long b = __ballot(pred);   // wave-wide on CDNA
    const int idx = (int)(b & 0xFFFULL);     // lanes 0..11 -> bits 0..11

    float* __restrict__ rowp = out + (size_t)row * NUM_CODES + lane * 4;
    #pragma unroll
    for (int i = 0; i < 16; ++i) {
        const int base = i * 256 + lane * 4;
        v4f v;
        v.x = (idx == base + 0) ? 1.0f : 0.0f;
        v.y = (idx == base + 1) ? 1.0f : 0.0f;
        v.z = (idx == base + 2) ? 1.0f : 0.0f;
        v.w = (idx == base + 3) ? 1.0f : 0.0f;
        __builtin_nontemporal_store(v, (v4f*)(rowp + i * 256));
    }
}

// aux_kl_loss = mean over positions of relu(BITS*ln2 - entropy - ln2).
// 32768 positions, one thread each; wave shuffle reduce -> LDS -> one
// atomicAdd per 256-thread block (128 atomics total).
__global__ __launch_bounds__(256)
void loss_kernel(const float* __restrict__ logits, float* __restrict__ loss_out)
{
    int pos = blockIdx.x * blockDim.x + threadIdx.x;
    float contrib = 0.f;
    if (pos < ROWS) {
        const float* lg = logits + pos * BITS;
        float H = 0.f;
        #pragma unroll
        for (int k = 0; k < BITS; ++k) {
            float x  = lg[k];
            float ax = fabsf(x);
            float e  = expf(-ax);
            // binary entropy of sigmoid(x): log1p(e^-|x|) + |x| * sigma(-|x|)
            H += log1pf(e) + ax * (e / (1.f + e));
        }
        float kl     = BITS * NATF - H;
        float hinged = kl - NATF;
        contrib = (hinged > 0.f) ? hinged * (1.f / (float)ROWS) : 0.f;
    }
    #pragma unroll
    for (int off = 32; off > 0; off >>= 1)
        contrib += __shfl_down(contrib, off, 64);

    __shared__ float ws[4];
    int wv = threadIdx.x >> 6;
    if ((threadIdx.x & 63) == 0) ws[wv] = contrib;
    __syncthreads();
    if (threadIdx.x == 0) {
        float s = ws[0] + ws[1] + ws[2] + ws[3];
        atomicAdd(loss_out, s);
    }
}

extern "C" void kernel_launch(void* const* d_in, const int* in_sizes, int n_in,
                              void* d_out, int out_size, void* d_ws, size_t ws_size,
                              hipStream_t stream)
{
    const float* logits    = (const float*)d_in[0];
    const float* rand_unif = (const float*)d_in[1];
    float* out = (float*)d_out;
    float* loss_out = out + (size_t)ROWS * NUM_CODES;  // element 134217728

    // zero the scalar accumulator (d_out is poisoned with 0xAA each call)
    (void)hipMemsetAsync((void*)loss_out, 0, sizeof(float), stream);

    loss_kernel<<<ROWS / 256, 256, 0, stream>>>(logits, loss_out);
    onehot_kernel<<<ROWS / 4, 256, 0, stream>>>(logits, rand_unif, out);
}